// Round 3
// baseline (1621.064 us; speedup 1.0000x reference)
//
#include <hip/hip_runtime.h>

typedef unsigned short u16;
typedef unsigned int u32;
typedef __attribute__((ext_vector_type(4))) float f32x4;
typedef __attribute__((ext_vector_type(8))) short bf16x8;
typedef __attribute__((ext_vector_type(8))) u16 u16x8;

// ---- helpers ----
__device__ __forceinline__ u16 f2b(float f) {
  union { float f; u32 u; } v; v.f = f;
  u32 r = v.u + 0x7FFFu + ((v.u >> 16) & 1u);
  return (u16)(r >> 16);
}
__device__ __forceinline__ float b2f(u16 h) {
  union { u32 u; float f; } v; v.u = ((u32)h) << 16;
  return v.f;
}
__device__ __forceinline__ void gload_lds16(const void* g, void* lds) {
  __builtin_amdgcn_global_load_lds(
      (__attribute__((address_space(1))) void*)(void*)g,
      (__attribute__((address_space(3))) void*)lds, 16, 0, 0);
}

// ---- cast x (fp32 -> bf16), vectorized 8/thread ----
__global__ __launch_bounds__(256) void cast_x_kernel(const float* __restrict__ x,
                                                     u16* __restrict__ xb, size_t n8) {
  size_t i = (size_t)blockIdx.x * blockDim.x + threadIdx.x;
  size_t stride = (size_t)gridDim.x * blockDim.x;
  for (; i < n8; i += stride) {
    const float4* p = (const float4*)(x + i * 8);
    float4 a = p[0], b = p[1];
    u16x8 o;
    o[0] = f2b(a.x); o[1] = f2b(a.y); o[2] = f2b(a.z); o[3] = f2b(a.w);
    o[4] = f2b(b.x); o[5] = f2b(b.y); o[6] = f2b(b.z); o[7] = f2b(b.w);
    *(u16x8*)(xb + i * 8) = o;
  }
}

// ---- transpose + cast: W[R][C] (fp32) -> WT[C][R] (bf16) ----
__global__ __launch_bounds__(256) void transpose_cast_kernel(const float* __restrict__ W,
                                                             u16* __restrict__ WT,
                                                             int R, int C) {
  __shared__ u16 tile[32][33];
  int rt = R >> 5;
  int tr = blockIdx.x % rt, tc = blockIdx.x / rt;
  int r0 = tr * 32, c0 = tc * 32;
#pragma unroll
  for (int i = 0; i < 4; ++i) {
    int r = (threadIdx.x >> 5) + i * 8, c = threadIdx.x & 31;
    tile[r][c] = f2b(W[(size_t)(r0 + r) * C + c0 + c]);
  }
  __syncthreads();
#pragma unroll
  for (int i = 0; i < 4; ++i) {
    int c = (threadIdx.x >> 5) + i * 8, r = threadIdx.x & 31;
    WT[(size_t)(c0 + c) * R + r0 + r] = tile[r][c];
  }
}

// ================= 256x256 GEMM, ring-2, 2 blocks/CU =================
// C[M][N] = A[M][K] * BT[N][K]^T ; bf16 in, fp32 acc.
// BM=BN=256, BK=32, 512 thr (8 waves, 2Mx4N), per-wave out 128x64.
// LDS: 2-deep ring of (A 16KB + B 16KB) = 64 KB -> 2 blocks/CU.
// Per K-tile: 2 phases, 2 barriers; stage t+1 early in phase A;
// vmcnt(0)+barrier at tile end. col16 ^= (row&3) swizzle both sides.
#define BM 256
#define BN 256
#define BK 32

template <bool OUT_BF16, bool BIAS, bool SOFTMAX, bool BATCHB>
__global__ __launch_bounds__(512, 4) void gemm256_kernel(
    const u16* __restrict__ A, const u16* __restrict__ BT, void* __restrict__ Cv,
    const float* __restrict__ bias, int N, int K, int lda, int ntile) {
  __shared__ u16 As[2 * 8192];
  __shared__ u16 Bs[2 * 8192];
  const int tid = threadIdx.x;
  const int wave = tid >> 6, lane = tid & 63;
  const int lr = lane & 15, hi = lane >> 4;
  const int wr = wave >> 2, wc = wave & 3;

  // bijective XCD swizzle (grid % 8 == 0)
  const int cpx = gridDim.x >> 3;
  const int wg = (blockIdx.x & 7) * cpx + (blockIdx.x >> 3);
  const int tm = wg / ntile, tn = wg % ntile;

  const size_t rowA0 = (size_t)tm * BM;
  const size_t rowB0 = (size_t)tn * BN;
  const u16* BTb = BATCHB ? (BT + (size_t)(tm >> 4) * 589824) : BT;  // per-batch B

  // staging: linear LDS dest, pre-swizzled global source col16
  const int rA = wave * 16 + (lane >> 2);          // 0..127
  const int csw = (lane & 3) ^ (rA & 3);
  const u16* srcA = A + (rowA0 + rA) * (size_t)lda + (csw << 3);
  const u16* srcB = BTb + (rowB0 + rA) * (size_t)K + (csw << 3);
  const int dstw = wave * 512;

  const int NT = K / BK;
  // read-side: logical (row, hi) lives at LDS (row, hi^(row&3))
  const int xs = ((hi ^ (lr & 3)) << 3);
  const int arow = wr * 128 + lr;
  const int brow = wc * 64 + lr;

  f32x4 acc[8][4] = {};

  // prologue: tile 0 -> buf 0
  gload_lds16(srcA, &As[dstw]);
  gload_lds16(srcA + (size_t)128 * lda, &As[dstw + 4096]);
  gload_lds16(srcB, &Bs[dstw]);
  gload_lds16(srcB + (size_t)128 * K, &Bs[dstw + 4096]);
  asm volatile("s_waitcnt vmcnt(0)" ::: "memory");
  __builtin_amdgcn_sched_barrier(0);
  __builtin_amdgcn_s_barrier();

  for (int t = 0; t < NT; ++t) {
    const int c = t & 1;
    const u16* Ab = &As[c * 8192];
    const u16* Bb = &Bs[c * 8192];

    // ---- phase A: read a0-3 + b0-3, stage tile t+1, MFMA acc[0..3]
    bf16x8 a0 = *(const bf16x8*)&Ab[(arow + 0) * 32 + xs];
    bf16x8 a1 = *(const bf16x8*)&Ab[(arow + 16) * 32 + xs];
    bf16x8 a2 = *(const bf16x8*)&Ab[(arow + 32) * 32 + xs];
    bf16x8 a3 = *(const bf16x8*)&Ab[(arow + 48) * 32 + xs];
    bf16x8 b0 = *(const bf16x8*)&Bb[(brow + 0) * 32 + xs];
    bf16x8 b1 = *(const bf16x8*)&Bb[(brow + 16) * 32 + xs];
    bf16x8 b2 = *(const bf16x8*)&Bb[(brow + 32) * 32 + xs];
    bf16x8 b3 = *(const bf16x8*)&Bb[(brow + 48) * 32 + xs];
    if (t + 1 < NT) {
      const u16* sa = srcA + (t + 1) * BK;
      const u16* sb = srcB + (t + 1) * BK;
      u16* Ad = &As[(c ^ 1) * 8192 + dstw];
      u16* Bd = &Bs[(c ^ 1) * 8192 + dstw];
      gload_lds16(sa, Ad);
      gload_lds16(sa + (size_t)128 * lda, Ad + 4096);
      gload_lds16(sb, Bd);
      gload_lds16(sb + (size_t)128 * K, Bd + 4096);
    }
    __builtin_amdgcn_s_barrier();
    asm volatile("s_waitcnt lgkmcnt(0)" ::: "memory");
    __builtin_amdgcn_sched_barrier(0);
    __builtin_amdgcn_s_setprio(1);
    acc[0][0] = __builtin_amdgcn_mfma_f32_16x16x32_bf16(a0, b0, acc[0][0], 0, 0, 0);
    acc[0][1] = __builtin_amdgcn_mfma_f32_16x16x32_bf16(a0, b1, acc[0][1], 0, 0, 0);
    acc[0][2] = __builtin_amdgcn_mfma_f32_16x16x32_bf16(a0, b2, acc[0][2], 0, 0, 0);
    acc[0][3] = __builtin_amdgcn_mfma_f32_16x16x32_bf16(a0, b3, acc[0][3], 0, 0, 0);
    acc[1][0] = __builtin_amdgcn_mfma_f32_16x16x32_bf16(a1, b0, acc[1][0], 0, 0, 0);
    acc[1][1] = __builtin_amdgcn_mfma_f32_16x16x32_bf16(a1, b1, acc[1][1], 0, 0, 0);
    acc[1][2] = __builtin_amdgcn_mfma_f32_16x16x32_bf16(a1, b2, acc[1][2], 0, 0, 0);
    acc[1][3] = __builtin_amdgcn_mfma_f32_16x16x32_bf16(a1, b3, acc[1][3], 0, 0, 0);
    acc[2][0] = __builtin_amdgcn_mfma_f32_16x16x32_bf16(a2, b0, acc[2][0], 0, 0, 0);
    acc[2][1] = __builtin_amdgcn_mfma_f32_16x16x32_bf16(a2, b1, acc[2][1], 0, 0, 0);
    acc[2][2] = __builtin_amdgcn_mfma_f32_16x16x32_bf16(a2, b2, acc[2][2], 0, 0, 0);
    acc[2][3] = __builtin_amdgcn_mfma_f32_16x16x32_bf16(a2, b3, acc[2][3], 0, 0, 0);
    acc[3][0] = __builtin_amdgcn_mfma_f32_16x16x32_bf16(a3, b0, acc[3][0], 0, 0, 0);
    acc[3][1] = __builtin_amdgcn_mfma_f32_16x16x32_bf16(a3, b1, acc[3][1], 0, 0, 0);
    acc[3][2] = __builtin_amdgcn_mfma_f32_16x16x32_bf16(a3, b2, acc[3][2], 0, 0, 0);
    acc[3][3] = __builtin_amdgcn_mfma_f32_16x16x32_bf16(a3, b3, acc[3][3], 0, 0, 0);
    __builtin_amdgcn_s_setprio(0);

    // ---- phase B: read a4-7, MFMA acc[4..7]  (no barrier before)
    bf16x8 a4 = *(const bf16x8*)&Ab[(arow + 64) * 32 + xs];
    bf16x8 a5 = *(const bf16x8*)&Ab[(arow + 80) * 32 + xs];
    bf16x8 a6 = *(const bf16x8*)&Ab[(arow + 96) * 32 + xs];
    bf16x8 a7 = *(const bf16x8*)&Ab[(arow + 112) * 32 + xs];
    asm volatile("s_waitcnt lgkmcnt(0)" ::: "memory");
    __builtin_amdgcn_sched_barrier(0);
    __builtin_amdgcn_s_setprio(1);
    acc[4][0] = __builtin_amdgcn_mfma_f32_16x16x32_bf16(a4, b0, acc[4][0], 0, 0, 0);
    acc[4][1] = __builtin_amdgcn_mfma_f32_16x16x32_bf16(a4, b1, acc[4][1], 0, 0, 0);
    acc[4][2] = __builtin_amdgcn_mfma_f32_16x16x32_bf16(a4, b2, acc[4][2], 0, 0, 0);
    acc[4][3] = __builtin_amdgcn_mfma_f32_16x16x32_bf16(a4, b3, acc[4][3], 0, 0, 0);
    acc[5][0] = __builtin_amdgcn_mfma_f32_16x16x32_bf16(a5, b0, acc[5][0], 0, 0, 0);
    acc[5][1] = __builtin_amdgcn_mfma_f32_16x16x32_bf16(a5, b1, acc[5][1], 0, 0, 0);
    acc[5][2] = __builtin_amdgcn_mfma_f32_16x16x32_bf16(a5, b2, acc[5][2], 0, 0, 0);
    acc[5][3] = __builtin_amdgcn_mfma_f32_16x16x32_bf16(a5, b3, acc[5][3], 0, 0, 0);
    acc[6][0] = __builtin_amdgcn_mfma_f32_16x16x32_bf16(a6, b0, acc[6][0], 0, 0, 0);
    acc[6][1] = __builtin_amdgcn_mfma_f32_16x16x32_bf16(a6, b1, acc[6][1], 0, 0, 0);
    acc[6][2] = __builtin_amdgcn_mfma_f32_16x16x32_bf16(a6, b2, acc[6][2], 0, 0, 0);
    acc[6][3] = __builtin_amdgcn_mfma_f32_16x16x32_bf16(a6, b3, acc[6][3], 0, 0, 0);
    acc[7][0] = __builtin_amdgcn_mfma_f32_16x16x32_bf16(a7, b0, acc[7][0], 0, 0, 0);
    acc[7][1] = __builtin_amdgcn_mfma_f32_16x16x32_bf16(a7, b1, acc[7][1], 0, 0, 0);
    acc[7][2] = __builtin_amdgcn_mfma_f32_16x16x32_bf16(a7, b2, acc[7][2], 0, 0, 0);
    acc[7][3] = __builtin_amdgcn_mfma_f32_16x16x32_bf16(a7, b3, acc[7][3], 0, 0, 0);
    __builtin_amdgcn_s_setprio(0);
    if (t + 1 < NT) asm volatile("s_waitcnt vmcnt(0)" ::: "memory");
    __builtin_amdgcn_sched_barrier(0);
    __builtin_amdgcn_s_barrier();
  }

  // ---- epilogue (+ optional fused softmax over each 64-col head chunk)
  const int orow = tm * BM + wr * 128;
  const int ocol = tn * BN + wc * 64;
  const bool do_sm = SOFTMAX && (tn * BN < 1536);
#pragma unroll
  for (int m = 0; m < 8; ++m) {
    if (do_sm) {
#pragma unroll
      for (int q = 0; q < 4; ++q) {
        float mx = fmaxf(fmaxf(acc[m][0][q], acc[m][1][q]),
                         fmaxf(acc[m][2][q], acc[m][3][q]));
#pragma unroll
        for (int s = 1; s <= 8; s <<= 1) mx = fmaxf(mx, __shfl_xor(mx, s, 64));
        float e0 = __expf(acc[m][0][q] - mx);
        float e1 = __expf(acc[m][1][q] - mx);
        float e2 = __expf(acc[m][2][q] - mx);
        float e3 = __expf(acc[m][3][q] - mx);
        float sum = e0 + e1 + e2 + e3;
#pragma unroll
        for (int s = 1; s <= 8; s <<= 1) sum += __shfl_xor(sum, s, 64);
        float inv = 1.0f / sum;
        acc[m][0][q] = e0 * inv; acc[m][1][q] = e1 * inv;
        acc[m][2][q] = e2 * inv; acc[m][3][q] = e3 * inv;
      }
    }
#pragma unroll
    for (int n = 0; n < 4; ++n) {
      const int col = ocol + n * 16 + lr;
      const float bv = BIAS ? bias[col] : 0.0f;
#pragma unroll
      for (int q = 0; q < 4; ++q) {
        const int row = orow + m * 16 + hi * 4 + q;
        const float v = acc[m][n][q] + bv;
        if (OUT_BF16) ((u16*)Cv)[(size_t)row * N + col] = f2b(v);
        else          ((float*)Cv)[(size_t)row * N + col] = v;
      }
    }
  }
}

// ---- context partials: partial[sp][bh][d][e] = sum_{n in split} k[n,d]*v[n,e] ----
#define NS 8
__global__ __launch_bounds__(256) void ctx_partial_kernel(const u16* __restrict__ qkv,
                                                          float* __restrict__ partial) {
  __shared__ u16 kT[64 * 136];
  __shared__ u16 vT[64 * 136];
  int bh = blockIdx.x / NS, sp = blockIdx.x % NS;
  int b = bh / 12, h = bh % 12;
  int tid = threadIdx.x, wave = tid >> 6, lane = tid & 63;
  int lr = lane & 15, lk = (lane >> 4) << 3;
  f32x4 acc[4] = {};
  int baseK = 768 + h * 64, baseV = 1536 + h * 64;

  for (int sub = 0; sub < 4; ++sub) {
    int nbase = b * 4096 + sp * 512 + sub * 128;
    __syncthreads();
#pragma unroll
    for (int it = 0; it < 4; ++it) {
      int s = it * 256 + tid;
      int n = s >> 3, c8 = (s & 7) * 8;
      u16x8 kv = *(const u16x8*)(qkv + (size_t)(nbase + n) * 2304 + baseK + c8);
      u16x8 vv = *(const u16x8*)(qkv + (size_t)(nbase + n) * 2304 + baseV + c8);
#pragma unroll
      for (int q = 0; q < 8; ++q) {
        kT[(c8 + q) * 136 + n] = kv[q];
        vT[(c8 + q) * 136 + n] = vv[q];
      }
    }
    __syncthreads();
#pragma unroll
    for (int ks = 0; ks < 4; ++ks) {
      bf16x8 af = *(const bf16x8*)&kT[(wave * 16 + lr) * 136 + ks * 32 + lk];
#pragma unroll
      for (int jt = 0; jt < 4; ++jt) {
        bf16x8 bfv = *(const bf16x8*)&vT[(jt * 16 + lr) * 136 + ks * 32 + lk];
        acc[jt] = __builtin_amdgcn_mfma_f32_16x16x32_bf16(af, bfv, acc[jt], 0, 0, 0);
      }
    }
  }
  float* dst = partial + ((size_t)sp * 96 + bh) * 4096;
#pragma unroll
  for (int jt = 0; jt < 4; ++jt)
#pragma unroll
    for (int q = 0; q < 4; ++q) {
      int d = wave * 16 + (lane >> 4) * 4 + q;
      int e = jt * 16 + lr;
      dst[d * 64 + e] = acc[jt][q];
    }
}

// ---- reduce partials -> ctxD[bh][d*64+e] bf16 (d-major) ----
__global__ __launch_bounds__(256) void ctx_reduce_kernel(const float* __restrict__ partial,
                                                         u16* __restrict__ ctxD) {
  int idx = blockIdx.x * 256 + threadIdx.x;   // 96*4096
  int bh = idx >> 12;
  int de = idx & 4095;
  float s = 0.0f;
#pragma unroll
  for (int sp = 0; sp < NS; ++sp) s += partial[((size_t)sp * 96 + bh) * 4096 + de];
  ctxD[(size_t)bh * 4096 + de] = f2b(s);
}

// ---- W2T[b][c'][h*64+d] = sum_e WprojT[c'][h*64+e] * ctxD[bh][d*64+e] ----
// grid: b(8) x h(12) x ct(6 tiles of 128 c'-rows); 256 thr, 4 waves.
__global__ __launch_bounds__(256) void make_w2_kernel(const u16* __restrict__ WprojT,
                                                      const u16* __restrict__ ctxD,
                                                      u16* __restrict__ BT2) {
  __shared__ u16 qs[128 * 64];
  __shared__ u16 cs[64 * 64];
  int bid = blockIdx.x;
  int b = bid / 72, rest = bid % 72;
  int h = rest / 6, ct = rest % 6;
  int bh = b * 12 + h;
  int tid = threadIdx.x, wave = tid >> 6, lane = tid & 63;
  int lr = lane & 15, lk = (lane >> 4) << 3;
#pragma unroll
  for (int it = 0; it < 4; ++it) {
    int u = it * 256 + tid;
    int r = u >> 3, c8 = (u & 7) * 8;
    gload_lds16(WprojT + (size_t)(ct * 128 + r) * 768 + h * 64 + c8,
                &qs[(it * 256 + wave * 64) * 8]);
  }
#pragma unroll
  for (int it = 0; it < 2; ++it) {
    int u = it * 256 + tid;
    gload_lds16(ctxD + (size_t)bh * 4096 + u * 8, &cs[(it * 256 + wave * 64) * 8]);
  }
  asm volatile("s_waitcnt vmcnt(0)" ::: "memory");
  __syncthreads();
  f32x4 acc[2][4] = {};
#pragma unroll
  for (int ks = 0; ks < 2; ++ks) {
    bf16x8 bv[4];
#pragma unroll
    for (int jt = 0; jt < 4; ++jt) bv[jt] = *(const bf16x8*)&cs[(jt * 16 + lr) * 64 + ks * 32 + lk];
#pragma unroll
    for (int i = 0; i < 2; ++i) {
      bf16x8 af = *(const bf16x8*)&qs[(wave * 32 + i * 16 + lr) * 64 + ks * 32 + lk];
#pragma unroll
      for (int jt = 0; jt < 4; ++jt)
        acc[i][jt] = __builtin_amdgcn_mfma_f32_16x16x32_bf16(af, bv[jt], acc[i][jt], 0, 0, 0);
    }
  }
#pragma unroll
  for (int i = 0; i < 2; ++i)
#pragma unroll
    for (int jt = 0; jt < 4; ++jt)
#pragma unroll
      for (int q = 0; q < 4; ++q) {
        int cp = ct * 128 + wave * 32 + i * 16 + (lane >> 4) * 4 + q;  // c' row
        int col = h * 64 + jt * 16 + lr;                               // hd col
        BT2[(size_t)b * 589824 + (size_t)cp * 768 + col] = f2b(acc[i][jt][q]);
      }
}

extern "C" void kernel_launch(void* const* d_in, const int* in_sizes, int n_in,
                              void* d_out, int out_size, void* d_ws, size_t ws_size,
                              hipStream_t stream) {
  const float* x = (const float*)d_in[0];
  const float* Wqkv = (const float*)d_in[1];
  const float* Wproj = (const float*)d_in[2];
  const float* bproj = (const float*)d_in[3];
  float* out = (float*)d_out;
  char* ws = (char*)d_ws;

  u16* xb      = (u16*)(ws);                     // 32768*768*2   = 50331648
  u16* WqkvT   = (u16*)(ws + 50331648);          // 2304*768*2    = 3538944
  u16* WprojT  = (u16*)(ws + 53870592);          // 768*768*2     = 1179648
  u16* qkv     = (u16*)(ws + 55050240);          // 32768*2304*2  = 150994944
  float* partial = (float*)(ws + 206045184);     // 8*96*4096*4   = 12582912
  u16* ctxD    = (u16*)(ws + 218628096);         // 96*4096*2     = 786432
  u16* BT2     = (u16*)(ws + 219414528);         // 8*768*768*2   = 9437184

  cast_x_kernel<<<2048, 256, 0, stream>>>(x, xb, (size_t)(32768ll * 768 / 8));
  transpose_cast_kernel<<<(768 / 32) * (2304 / 32), 256, 0, stream>>>(Wqkv, WqkvT, 768, 2304);
  transpose_cast_kernel<<<(768 / 32) * (768 / 32), 256, 0, stream>>>(Wproj, WprojT, 768, 768);

  // GEMM1: qkv = xb @ WqkvT^T, fused softmax on cols [0,1536)
  gemm256_kernel<true, false, true, false><<<(32768 / 256) * (2304 / 256), 512, 0, stream>>>(
      xb, WqkvT, (void*)qkv, nullptr, 2304, 768, 768, 2304 / 256);

  ctx_partial_kernel<<<96 * NS, 256, 0, stream>>>(qkv, partial);
  ctx_reduce_kernel<<<(96 * 4096) / 256, 256, 0, stream>>>(partial, ctxD);
  make_w2_kernel<<<8 * 12 * 6, 256, 0, stream>>>(WprojT, ctxD, BT2);

  // GEMM3: out = q(from qkv, lda=2304) @ W2T_b^T + bias  (per-batch B)
  gemm256_kernel<false, true, false, true><<<(32768 / 256) * (768 / 256), 512, 0, stream>>>(
      qkv, BT2, (void*)out, bproj, 768, 768, 2304, 768 / 256);
}

// Round 4
// 358.305 us; speedup vs baseline: 4.5243x; 4.5243x over previous
//
#include <hip/hip_runtime.h>

typedef unsigned short u16;
typedef unsigned int u32;
typedef __attribute__((ext_vector_type(4))) float f32x4;
typedef __attribute__((ext_vector_type(16))) float f32x16;
typedef __attribute__((ext_vector_type(8))) short bf16x8;
typedef __attribute__((ext_vector_type(8))) u16 u16x8;

// ---- helpers ----
__device__ __forceinline__ u16 f2b(float f) {
  union { float f; u32 u; } v; v.f = f;
  u32 r = v.u + 0x7FFFu + ((v.u >> 16) & 1u);
  return (u16)(r >> 16);
}
__device__ __forceinline__ float b2f(u16 h) {
  union { u32 u; float f; } v; v.u = ((u32)h) << 16;
  return v.f;
}
__device__ __forceinline__ void gload_lds16(const void* g, void* lds) {
  __builtin_amdgcn_global_load_lds(
      (__attribute__((address_space(1))) void*)(void*)g,
      (__attribute__((address_space(3))) void*)lds, 16, 0, 0);
}
// swizzle within an 8KB k-slice slot (rows of 32B): XOR byte bits 4-5 with bits 7-8
__device__ __forceinline__ int swz8k(int x) { return x ^ (((x >> 7) & 3) << 4); }

// ---- cast x (fp32 -> bf16), vectorized 8/thread ----
__global__ __launch_bounds__(256) void cast_x_kernel(const float* __restrict__ x,
                                                     u16* __restrict__ xb, size_t n8) {
  size_t i = (size_t)blockIdx.x * blockDim.x + threadIdx.x;
  size_t stride = (size_t)gridDim.x * blockDim.x;
  for (; i < n8; i += stride) {
    const float4* p = (const float4*)(x + i * 8);
    float4 a = p[0], b = p[1];
    u16x8 o;
    o[0] = f2b(a.x); o[1] = f2b(a.y); o[2] = f2b(a.z); o[3] = f2b(a.w);
    o[4] = f2b(b.x); o[5] = f2b(b.y); o[6] = f2b(b.z); o[7] = f2b(b.w);
    *(u16x8*)(xb + i * 8) = o;
  }
}

// ---- transpose + cast: W[R][C] (fp32) -> WT[C][R] (bf16) ----
__global__ __launch_bounds__(256) void transpose_cast_kernel(const float* __restrict__ W,
                                                             u16* __restrict__ WT,
                                                             int R, int C) {
  __shared__ u16 tile[32][33];
  int rt = R >> 5;
  int tr = blockIdx.x % rt, tc = blockIdx.x / rt;
  int r0 = tr * 32, c0 = tc * 32;
#pragma unroll
  for (int i = 0; i < 4; ++i) {
    int r = (threadIdx.x >> 5) + i * 8, c = threadIdx.x & 31;
    tile[r][c] = f2b(W[(size_t)(r0 + r) * C + c0 + c]);
  }
  __syncthreads();
#pragma unroll
  for (int i = 0; i < 4; ++i) {
    int c = (threadIdx.x >> 5) + i * 8, r = threadIdx.x & 31;
    WT[(size_t)(c0 + c) * R + r0 + r] = tile[r][c];
  }
}

// ============ 256x256 GEMM, 32x32x16 MFMA, 8-slot k-slice ring ============
// C[M][N] = A[M][K] * BT[N][K]^T ; bf16 in, fp32 acc. K=768 fixed.
// 512 thr (8 waves, 2Mx4N), per-wave out 128x64 as 4x2 frags of 32x32.
// K-slices of 16; LDS ring of 8 slots x (A 8KB + B 8KB) = 128 KB.
// Per phase: 6 ds_read_b128 + stage slice P+7 (2 gload_lds) + vmcnt(12)
// + barrier + lgkmcnt(0) + 8 MFMA + barrier.  vmcnt never drains mid-loop.
template <bool OUT_BF16, bool BIAS, bool SOFTMAX, bool BATCHB>
__global__ __launch_bounds__(512, 2) void gemm256_kernel(
    const u16* __restrict__ A, const u16* __restrict__ BT, void* __restrict__ Cv,
    const float* __restrict__ bias, int N, int lda, int ntile) {
  constexpr int K = 768;
  constexpr int NK = 48;          // K/16 slices
  __shared__ __align__(16) u16 As[8 * 4096];
  __shared__ __align__(16) u16 Bs[8 * 4096];
  const int tid = threadIdx.x;
  const int wave = tid >> 6, lane = tid & 63;
  const int l31 = lane & 31, lhi = lane >> 5;
  const int wr = wave >> 2, wc = wave & 3;

  // bijective XCD swizzle (grid % 8 == 0)
  const int cpx = gridDim.x >> 3;
  const int wg = (blockIdx.x & 7) * cpx + (blockIdx.x >> 3);
  const int tm = wg / ntile, tn = wg % ntile;

  const size_t rowA0 = (size_t)tm * 256;
  const size_t rowB0 = (size_t)tn * 256;
  const u16* BTb = BATCHB ? (BT + (size_t)(tm >> 4) * 589824) : BT;

  // ---- staging constants: linear LDS dest, inverse-swizzled global source
  const int rel = wave * 1024 + lane * 16;     // dest byte offset in slot
  const int srel = swz8k(rel);
  const int sr = srel >> 5;                    // source row within tile
  const int skoff = (srel & 31) >> 1;          // source k-offset within slice
  const u16* srcA0 = A + (rowA0 + sr) * (size_t)lda + skoff;
  const u16* srcB0 = BTb + (rowB0 + sr) * (size_t)K + skoff;

  // ---- read-side swizzled byte offsets (loop-invariant)
  int aoff[4], boff[2];
#pragma unroll
  for (int mf = 0; mf < 4; ++mf)
    aoff[mf] = swz8k((wr * 128 + mf * 32 + l31) * 32 + lhi * 16) >> 1;  // u16 idx
#pragma unroll
  for (int nf = 0; nf < 2; ++nf)
    boff[nf] = swz8k((wc * 64 + nf * 32 + l31) * 32 + lhi * 16) >> 1;

  f32x16 acc[4][2] = {};

#define STAGE(ks)                                                        \
  {                                                                      \
    const int _s = (ks) & 7;                                             \
    gload_lds16(srcA0 + (size_t)(ks) * 16, &As[_s * 4096 + wave * 512]); \
    gload_lds16(srcB0 + (size_t)(ks) * 16, &Bs[_s * 4096 + wave * 512]); \
  }

  // prologue: stage slices 0..6 (14 loads)
#pragma unroll
  for (int ks = 0; ks < 7; ++ks) STAGE(ks);
  asm volatile("s_waitcnt vmcnt(12)" ::: "memory");   // slice 0 landed
  __builtin_amdgcn_sched_barrier(0);
  __builtin_amdgcn_s_barrier();

#define PHASE_BODY(SLOT)                                                   \
  bf16x8 a0 = *(const bf16x8*)&As[(SLOT)*4096 + aoff[0]];                  \
  bf16x8 a1 = *(const bf16x8*)&As[(SLOT)*4096 + aoff[1]];                  \
  bf16x8 a2 = *(const bf16x8*)&As[(SLOT)*4096 + aoff[2]];                  \
  bf16x8 a3 = *(const bf16x8*)&As[(SLOT)*4096 + aoff[3]];                  \
  bf16x8 b0 = *(const bf16x8*)&Bs[(SLOT)*4096 + boff[0]];                  \
  bf16x8 b1 = *(const bf16x8*)&Bs[(SLOT)*4096 + boff[1]];

#define PHASE_MFMA()                                                          \
  __builtin_amdgcn_s_barrier();                                               \
  asm volatile("s_waitcnt lgkmcnt(0)" ::: "memory");                          \
  __builtin_amdgcn_sched_barrier(0);                                          \
  __builtin_amdgcn_s_setprio(1);                                              \
  acc[0][0] = __builtin_amdgcn_mfma_f32_32x32x16_bf16(a0, b0, acc[0][0], 0, 0, 0); \
  acc[0][1] = __builtin_amdgcn_mfma_f32_32x32x16_bf16(a0, b1, acc[0][1], 0, 0, 0); \
  acc[1][0] = __builtin_amdgcn_mfma_f32_32x32x16_bf16(a1, b0, acc[1][0], 0, 0, 0); \
  acc[1][1] = __builtin_amdgcn_mfma_f32_32x32x16_bf16(a1, b1, acc[1][1], 0, 0, 0); \
  acc[2][0] = __builtin_amdgcn_mfma_f32_32x32x16_bf16(a2, b0, acc[2][0], 0, 0, 0); \
  acc[2][1] = __builtin_amdgcn_mfma_f32_32x32x16_bf16(a2, b1, acc[2][1], 0, 0, 0); \
  acc[3][0] = __builtin_amdgcn_mfma_f32_32x32x16_bf16(a3, b0, acc[3][0], 0, 0, 0); \
  acc[3][1] = __builtin_amdgcn_mfma_f32_32x32x16_bf16(a3, b1, acc[3][1], 0, 0, 0); \
  __builtin_amdgcn_s_setprio(0);                                              \
  __builtin_amdgcn_s_barrier();                                               \
  __builtin_amdgcn_sched_barrier(0);

  // main: 5 revolutions of 8 phases (slices 0..39), staging slice P+7
  for (int pp = 0; pp < NK - 8; pp += 8) {
#pragma unroll
    for (int u = 0; u < 8; ++u) {
      PHASE_BODY(u)
      STAGE(pp + u + 7);
      asm volatile("s_waitcnt vmcnt(12)" ::: "memory");
      __builtin_amdgcn_sched_barrier(0);
      PHASE_MFMA()
    }
  }
  // epilogue revolution: slices 40..47
#pragma unroll
  for (int u = 0; u < 8; ++u) {
    PHASE_BODY(u)
    if (u == 0) STAGE(47);
    if (u == 0)      asm volatile("s_waitcnt vmcnt(12)" ::: "memory");
    else if (u == 1) asm volatile("s_waitcnt vmcnt(10)" ::: "memory");
    else if (u == 2) asm volatile("s_waitcnt vmcnt(8)" ::: "memory");
    else if (u == 3) asm volatile("s_waitcnt vmcnt(6)" ::: "memory");
    else if (u == 4) asm volatile("s_waitcnt vmcnt(4)" ::: "memory");
    else if (u == 5) asm volatile("s_waitcnt vmcnt(2)" ::: "memory");
    else             asm volatile("s_waitcnt vmcnt(0)" ::: "memory");
    __builtin_amdgcn_sched_barrier(0);
    PHASE_MFMA()
  }
#undef STAGE
#undef PHASE_BODY
#undef PHASE_MFMA

  // ---- epilogue: optional fused softmax (over each 64-col head chunk) + store
  const int orow = tm * 256 + wr * 128;
  const int ocol = tn * 256 + wc * 64;
  if (SOFTMAX && ocol < 1536) {
#pragma unroll
    for (int mf = 0; mf < 4; ++mf)
#pragma unroll
      for (int q = 0; q < 16; ++q) {
        float v0 = acc[mf][0][q], v1 = acc[mf][1][q];
        float mx = fmaxf(v0, v1);
#pragma unroll
        for (int s = 1; s <= 16; s <<= 1) mx = fmaxf(mx, __shfl_xor(mx, s, 64));
        float e0 = __expf(v0 - mx), e1 = __expf(v1 - mx);
        float sm = e0 + e1;
#pragma unroll
        for (int s = 1; s <= 16; s <<= 1) sm += __shfl_xor(sm, s, 64);
        float inv = 1.0f / sm;
        acc[mf][0][q] = e0 * inv;
        acc[mf][1][q] = e1 * inv;
      }
  }
#pragma unroll
  for (int nf = 0; nf < 2; ++nf) {
    const int col = ocol + nf * 32 + l31;
    const float bv = BIAS ? bias[col] : 0.0f;
#pragma unroll
    for (int mf = 0; mf < 4; ++mf)
#pragma unroll
      for (int q = 0; q < 16; ++q) {
        const int row = orow + mf * 32 + (q & 3) + 8 * (q >> 2) + 4 * lhi;
        const float v = acc[mf][nf][q] + bv;
        if (OUT_BF16) ((u16*)Cv)[(size_t)row * N + col] = f2b(v);
        else          ((float*)Cv)[(size_t)row * N + col] = v;
      }
  }
}

// ---- context partials: partial[sp][bh][d][e] = sum_{n in split} k[n,d]*v[n,e] ----
#define NS 8
__global__ __launch_bounds__(256) void ctx_partial_kernel(const u16* __restrict__ qkv,
                                                          float* __restrict__ partial) {
  __shared__ u16 kT[64 * 136];
  __shared__ u16 vT[64 * 136];
  int bh = blockIdx.x / NS, sp = blockIdx.x % NS;
  int b = bh / 12, h = bh % 12;
  int tid = threadIdx.x, wave = tid >> 6, lane = tid & 63;
  int lr = lane & 15, lk = (lane >> 4) << 3;
  f32x4 acc[4] = {};
  int baseK = 768 + h * 64, baseV = 1536 + h * 64;

  for (int sub = 0; sub < 4; ++sub) {
    int nbase = b * 4096 + sp * 512 + sub * 128;
    __syncthreads();
#pragma unroll
    for (int it = 0; it < 4; ++it) {
      int s = it * 256 + tid;
      int n = s >> 3, c8 = (s & 7) * 8;
      u16x8 kv = *(const u16x8*)(qkv + (size_t)(nbase + n) * 2304 + baseK + c8);
      u16x8 vv = *(const u16x8*)(qkv + (size_t)(nbase + n) * 2304 + baseV + c8);
#pragma unroll
      for (int q = 0; q < 8; ++q) {
        kT[(c8 + q) * 136 + n] = kv[q];
        vT[(c8 + q) * 136 + n] = vv[q];
      }
    }
    __syncthreads();
#pragma unroll
    for (int ks = 0; ks < 4; ++ks) {
      bf16x8 af = *(const bf16x8*)&kT[(wave * 16 + lr) * 136 + ks * 32 + lk];
#pragma unroll
      for (int jt = 0; jt < 4; ++jt) {
        bf16x8 bfv = *(const bf16x8*)&vT[(jt * 16 + lr) * 136 + ks * 32 + lk];
        acc[jt] = __builtin_amdgcn_mfma_f32_16x16x32_bf16(af, bfv, acc[jt], 0, 0, 0);
      }
    }
  }
  float* dst = partial + ((size_t)sp * 96 + bh) * 4096;
#pragma unroll
  for (int jt = 0; jt < 4; ++jt)
#pragma unroll
    for (int q = 0; q < 4; ++q) {
      int d = wave * 16 + (lane >> 4) * 4 + q;
      int e = jt * 16 + lr;
      dst[d * 64 + e] = acc[jt][q];
    }
}

// ---- reduce partials -> ctxD[bh][d*64+e] bf16 (d-major) ----
__global__ __launch_bounds__(256) void ctx_reduce_kernel(const float* __restrict__ partial,
                                                         u16* __restrict__ ctxD) {
  int idx = blockIdx.x * 256 + threadIdx.x;   // 96*4096
  int bh = idx >> 12;
  int de = idx & 4095;
  float s = 0.0f;
#pragma unroll
  for (int sp = 0; sp < NS; ++sp) s += partial[((size_t)sp * 96 + bh) * 4096 + de];
  ctxD[(size_t)bh * 4096 + de] = f2b(s);
}

// ---- W2T[b][c'][h*64+d] = sum_e WprojT[c'][h*64+e] * ctxD[bh][d*64+e] ----
__global__ __launch_bounds__(256) void make_w2_kernel(const u16* __restrict__ WprojT,
                                                      const u16* __restrict__ ctxD,
                                                      u16* __restrict__ BT2) {
  __shared__ u16 qs[128 * 64];
  __shared__ u16 cs[64 * 64];
  int bid = blockIdx.x;
  int b = bid / 72, rest = bid % 72;
  int h = rest / 6, ct = rest % 6;
  int bh = b * 12 + h;
  int tid = threadIdx.x, wave = tid >> 6, lane = tid & 63;
  int lr = lane & 15, lk = (lane >> 4) << 3;
#pragma unroll
  for (int it = 0; it < 4; ++it) {
    int u = it * 256 + tid;
    int r = u >> 3, c8 = (u & 7) * 8;
    gload_lds16(WprojT + (size_t)(ct * 128 + r) * 768 + h * 64 + c8,
                &qs[(it * 256 + wave * 64) * 8]);
  }
#pragma unroll
  for (int it = 0; it < 2; ++it) {
    int u = it * 256 + tid;
    gload_lds16(ctxD + (size_t)bh * 4096 + u * 8, &cs[(it * 256 + wave * 64) * 8]);
  }
  asm volatile("s_waitcnt vmcnt(0)" ::: "memory");
  __syncthreads();
  f32x4 acc[2][4] = {};
#pragma unroll
  for (int ks = 0; ks < 2; ++ks) {
    bf16x8 bv[4];
#pragma unroll
    for (int jt = 0; jt < 4; ++jt) bv[jt] = *(const bf16x8*)&cs[(jt * 16 + lr) * 64 + ks * 32 + lk];
#pragma unroll
    for (int i = 0; i < 2; ++i) {
      bf16x8 af = *(const bf16x8*)&qs[(wave * 32 + i * 16 + lr) * 64 + ks * 32 + lk];
#pragma unroll
      for (int jt = 0; jt < 4; ++jt)
        acc[i][jt] = __builtin_amdgcn_mfma_f32_16x16x32_bf16(af, bv[jt], acc[i][jt], 0, 0, 0);
    }
  }
#pragma unroll
  for (int i = 0; i < 2; ++i)
#pragma unroll
    for (int jt = 0; jt < 4; ++jt)
#pragma unroll
      for (int q = 0; q < 4; ++q) {
        int cp = ct * 128 + wave * 32 + i * 16 + (lane >> 4) * 4 + q;
        int col = h * 64 + jt * 16 + lr;
        BT2[(size_t)b * 589824 + (size_t)cp * 768 + col] = f2b(acc[i][jt][q]);
      }
}

extern "C" void kernel_launch(void* const* d_in, const int* in_sizes, int n_in,
                              void* d_out, int out_size, void* d_ws, size_t ws_size,
                              hipStream_t stream) {
  const float* x = (const float*)d_in[0];
  const float* Wqkv = (const float*)d_in[1];
  const float* Wproj = (const float*)d_in[2];
  const float* bproj = (const float*)d_in[3];
  float* out = (float*)d_out;
  char* ws = (char*)d_ws;

  u16* xb      = (u16*)(ws);                     // 32768*768*2   = 50331648
  u16* WqkvT   = (u16*)(ws + 50331648);          // 2304*768*2    = 3538944
  u16* WprojT  = (u16*)(ws + 53870592);          // 768*768*2     = 1179648
  u16* qkv     = (u16*)(ws + 55050240);          // 32768*2304*2  = 150994944
  float* partial = (float*)(ws + 206045184);     // 8*96*4096*4   = 12582912
  u16* ctxD    = (u16*)(ws + 218628096);         // 96*4096*2     = 786432
  u16* BT2     = (u16*)(ws + 219414528);         // 8*768*768*2   = 9437184

  cast_x_kernel<<<2048, 256, 0, stream>>>(x, xb, (size_t)(32768ll * 768 / 8));
  transpose_cast_kernel<<<(768 / 32) * (2304 / 32), 256, 0, stream>>>(Wqkv, WqkvT, 768, 2304);
  transpose_cast_kernel<<<(768 / 32) * (768 / 32), 256, 0, stream>>>(Wproj, WprojT, 768, 768);

  // GEMM1: qkv = xb @ WqkvT^T, fused softmax on cols [0,1536)
  gemm256_kernel<true, false, true, false><<<(32768 / 256) * (2304 / 256), 512, 0, stream>>>(
      xb, WqkvT, (void*)qkv, nullptr, 2304, 768, 2304 / 256);

  ctx_partial_kernel<<<96 * NS, 256, 0, stream>>>(qkv, partial);
  ctx_reduce_kernel<<<(96 * 4096) / 256, 256, 0, stream>>>(partial, ctxD);
  make_w2_kernel<<<8 * 12 * 6, 256, 0, stream>>>(WprojT, ctxD, BT2);

  // GEMM3: out = q(from qkv, lda=2304) @ W2T_b^T + bias  (per-batch B)
  gemm256_kernel<false, true, false, true><<<(32768 / 256) * (768 / 256), 512, 0, stream>>>(
      qkv, BT2, (void*)out, bproj, 768, 2304, 768 / 256);
}

// Round 5
// 294.105 us; speedup vs baseline: 5.5119x; 1.2183x over previous
//
#include <hip/hip_runtime.h>

typedef unsigned short u16;
typedef unsigned int u32;
typedef __attribute__((ext_vector_type(4))) float f32x4;
typedef __attribute__((ext_vector_type(8))) short bf16x8;
typedef __attribute__((ext_vector_type(8))) u16 u16x8;

// ---- helpers ----
__device__ __forceinline__ u16 f2b(float f) {
  union { float f; u32 u; } v; v.f = f;
  u32 r = v.u + 0x7FFFu + ((v.u >> 16) & 1u);
  return (u16)(r >> 16);
}
__device__ __forceinline__ float b2f(u16 h) {
  union { u32 u; float f; } v; v.u = ((u32)h) << 16;
  return v.f;
}
__device__ __forceinline__ void gload_lds16(const void* g, void* lds) {
  __builtin_amdgcn_global_load_lds(
      (__attribute__((address_space(1))) void*)(void*)g,
      (__attribute__((address_space(3))) void*)lds, 16, 0, 0);
}

// ---- cast x (fp32 -> bf16), vectorized 8/thread ----
__global__ __launch_bounds__(256) void cast_x_kernel(const float* __restrict__ x,
                                                     u16* __restrict__ xb, size_t n8) {
  size_t i = (size_t)blockIdx.x * blockDim.x + threadIdx.x;
  size_t stride = (size_t)gridDim.x * blockDim.x;
  for (; i < n8; i += stride) {
    const float4* p = (const float4*)(x + i * 8);
    float4 a = p[0], b = p[1];
    u16x8 o;
    o[0] = f2b(a.x); o[1] = f2b(a.y); o[2] = f2b(a.z); o[3] = f2b(a.w);
    o[4] = f2b(b.x); o[5] = f2b(b.y); o[6] = f2b(b.z); o[7] = f2b(b.w);
    *(u16x8*)(xb + i * 8) = o;
  }
}

// ---- transpose + cast: W[R][C] (fp32) -> WT[C][R] (bf16) ----
__global__ __launch_bounds__(256) void transpose_cast_kernel(const float* __restrict__ W,
                                                             u16* __restrict__ WT,
                                                             int R, int C) {
  __shared__ u16 tile[32][33];
  int rt = R >> 5;
  int tr = blockIdx.x % rt, tc = blockIdx.x / rt;
  int r0 = tr * 32, c0 = tc * 32;
#pragma unroll
  for (int i = 0; i < 4; ++i) {
    int r = (threadIdx.x >> 5) + i * 8, c = threadIdx.x & 31;
    tile[r][c] = f2b(W[(size_t)(r0 + r) * C + c0 + c]);
  }
  __syncthreads();
#pragma unroll
  for (int i = 0; i < 4; ++i) {
    int c = (threadIdx.x >> 5) + i * 8, r = threadIdx.x & 31;
    WT[(size_t)(c0 + c) * R + r0 + r] = tile[r][c];
  }
}

// ============== 256x256 8-phase GEMM (m201 template port) ==============
// C[M][N] = A[M][K] * BT[N][K]^T ; bf16 in, fp32 acc ; K = 768 (NT=12 BK=64).
// 512 thr, 8 waves (2M x 4N); per-wave C = 128x64 = 8 mfrag x 4 nfrag (16x16).
// LDS: A,B each 2 tiles x 2 halves x 16KB = 128 KB total.
// Per K-tile, 4 phases x {ds_read subtile | stage 1 half-tile | barrier |
// lgkmcnt(0) | 16 MFMA | barrier}; vmcnt(6) only at phase 4 (3 halves in
// flight); st_16x32 swizzle both sides (inverse-swizzled source, swizzled read).
template <bool OUT_BF16, bool BIAS, bool SOFTMAX, bool BATCHB>
__global__ __launch_bounds__(512, 2) void gemm256_kernel(
    const u16* __restrict__ A, const u16* __restrict__ BT, void* __restrict__ Cv,
    const float* __restrict__ bias, int N, int lda, int ntile) {
  constexpr int K = 768;
  constexpr int NT = 12;
  __shared__ __align__(16) u16 As[32768];   // [2 buf][2 half][8192 u16]
  __shared__ __align__(16) u16 Bs[32768];
  const int tid = threadIdx.x;
  const int wave = tid >> 6, lane = tid & 63;
  const int lr = lane & 15, hi = lane >> 4;
  const int wr = wave >> 2, wc = wave & 3;

  // bijective XCD swizzle (grid % 8 == 0)
  const int cpx = gridDim.x >> 3;
  const int wg = (blockIdx.x & 7) * cpx + (blockIdx.x >> 3);
  const int tm = wg / ntile, tn = wg % ntile;

  const size_t rowA0 = (size_t)tm * 256;
  const size_t rowB0 = (size_t)tn * 256;
  const u16* BTb = BATCHB ? (BT + (size_t)(tm >> 4) * 589824) : BT;

  // ---- staging source (inverse st_16x32 swizzle): LDS[d] = G[swz(d)]
  const int d0 = tid * 16;
  const int s0 = d0 ^ (((d0 >> 9) & 1) << 5);
  const int srow = s0 >> 7;            // 0..63 (part1 adds 64)
  const int sk = (s0 & 127) >> 1;      // u16 col 0..63
  const u16* pA0 = A + (rowA0 + srow) * (size_t)lda + sk;
  const u16* pB0 = BTb + (rowB0 + srow) * (size_t)K + sk;
  const size_t a64 = (size_t)64 * lda;
  const size_t a128 = (size_t)128 * lda;
  u16* Adst = As + wave * 512;
  u16* Bdst = Bs + wave * 512;

  // ---- read-side swizzled bases (flip = row-bit2 = lr-bit2 -> byte bit5)
  const int flip = ((lr >> 2) & 1) << 5;
  const int baseA = (((wr * 64 + lr) * 128 + hi * 16) ^ flip) >> 1;
  const int baseB = ((((wc & 1) * 64 + lr) * 128 + hi * 16) ^ flip) >> 1;
  const int bhalf = (wc >> 1) * 8192;   // which B half this wave reads

  f32x4 acc[8][4] = {};

#define STG_A(tt, hf)                                                   \
  { const u16* _s = pA0 + (size_t)(tt) * 64 + (size_t)(hf) * a128;      \
    u16* _d = Adst + (((tt) & 1) * 2 + (hf)) * 8192;                    \
    gload_lds16(_s, _d); gload_lds16(_s + a64, _d + 4096); }
#define STG_B(tt, hf)                                                   \
  { const u16* _s = pB0 + (size_t)(tt) * 64 + (size_t)(hf) * (128 * K); \
    u16* _d = Bdst + (((tt) & 1) * 2 + (hf)) * 8192;                    \
    gload_lds16(_s, _d); gload_lds16(_s + 64 * K, _d + 4096); }

  // prologue: halves 0..6 (tile0 complete + A0,B0,B1 of tile1)
  STG_A(0, 0); STG_B(0, 0); STG_B(0, 1); STG_A(0, 1);
  STG_A(1, 0); STG_B(1, 0); STG_B(1, 1);
  asm volatile("s_waitcnt vmcnt(6)" ::: "memory");   // tile 0 landed
  __builtin_amdgcn_sched_barrier(0);
  __builtin_amdgcn_s_barrier();

  for (int t = 0; t < NT; ++t) {
    const u16* Ab = As + (t & 1) * 16384;
    const u16* Bb = Bs + (t & 1) * 16384 + bhalf;
    bf16x8 a[8], a2[8], b[4], b2[4];

    // ---------- phase 1: read A-mh0 (8) + B-nf01 (4); stage Ah1(t+1)
#pragma unroll
    for (int mf = 0; mf < 4; ++mf) {
      a[mf * 2 + 0] = *(const bf16x8*)&Ab[baseA + mf * 1024];
      a[mf * 2 + 1] = *(const bf16x8*)&Ab[baseA + mf * 1024 + 32];
    }
    b[0] = *(const bf16x8*)&Bb[baseB];
    b[1] = *(const bf16x8*)&Bb[baseB + 32];
    b[2] = *(const bf16x8*)&Bb[baseB + 1024];
    b[3] = *(const bf16x8*)&Bb[baseB + 1024 + 32];
    if (t + 1 < NT) STG_A(t + 1, 1);
    __builtin_amdgcn_s_barrier();
    asm volatile("s_waitcnt lgkmcnt(0)" ::: "memory");
    __builtin_amdgcn_sched_barrier(0);
    __builtin_amdgcn_s_setprio(1);
#pragma unroll
    for (int mf = 0; mf < 4; ++mf)
#pragma unroll
      for (int nf = 0; nf < 2; ++nf) {
        acc[mf][nf] = __builtin_amdgcn_mfma_f32_16x16x32_bf16(a[mf * 2], b[nf * 2], acc[mf][nf], 0, 0, 0);
        acc[mf][nf] = __builtin_amdgcn_mfma_f32_16x16x32_bf16(a[mf * 2 + 1], b[nf * 2 + 1], acc[mf][nf], 0, 0, 0);
      }
    __builtin_amdgcn_s_setprio(0);
    __builtin_amdgcn_s_barrier();

    // ---------- phase 2: read B-nf23 (4); stage Ah0(t+2)
    b2[0] = *(const bf16x8*)&Bb[baseB + 2048];
    b2[1] = *(const bf16x8*)&Bb[baseB + 2048 + 32];
    b2[2] = *(const bf16x8*)&Bb[baseB + 3072];
    b2[3] = *(const bf16x8*)&Bb[baseB + 3072 + 32];
    if (t + 2 < NT) STG_A(t + 2, 0);
    __builtin_amdgcn_s_barrier();
    asm volatile("s_waitcnt lgkmcnt(0)" ::: "memory");
    __builtin_amdgcn_sched_barrier(0);
    __builtin_amdgcn_s_setprio(1);
#pragma unroll
    for (int mf = 0; mf < 4; ++mf)
#pragma unroll
      for (int nf = 0; nf < 2; ++nf) {
        acc[mf][nf + 2] = __builtin_amdgcn_mfma_f32_16x16x32_bf16(a[mf * 2], b2[nf * 2], acc[mf][nf + 2], 0, 0, 0);
        acc[mf][nf + 2] = __builtin_amdgcn_mfma_f32_16x16x32_bf16(a[mf * 2 + 1], b2[nf * 2 + 1], acc[mf][nf + 2], 0, 0, 0);
      }
    __builtin_amdgcn_s_setprio(0);
    __builtin_amdgcn_s_barrier();

    // ---------- phase 3: read A-mh1 (8); stage Bh0(t+2)
#pragma unroll
    for (int mf = 0; mf < 4; ++mf) {
      a2[mf * 2 + 0] = *(const bf16x8*)&Ab[8192 + baseA + mf * 1024];
      a2[mf * 2 + 1] = *(const bf16x8*)&Ab[8192 + baseA + mf * 1024 + 32];
    }
    if (t + 2 < NT) STG_B(t + 2, 0);
    __builtin_amdgcn_s_barrier();
    asm volatile("s_waitcnt lgkmcnt(0)" ::: "memory");
    __builtin_amdgcn_sched_barrier(0);
    __builtin_amdgcn_s_setprio(1);
#pragma unroll
    for (int mf = 0; mf < 4; ++mf)
#pragma unroll
      for (int nf = 0; nf < 2; ++nf) {
        acc[mf + 4][nf] = __builtin_amdgcn_mfma_f32_16x16x32_bf16(a2[mf * 2], b[nf * 2], acc[mf + 4][nf], 0, 0, 0);
        acc[mf + 4][nf] = __builtin_amdgcn_mfma_f32_16x16x32_bf16(a2[mf * 2 + 1], b[nf * 2 + 1], acc[mf + 4][nf], 0, 0, 0);
      }
    __builtin_amdgcn_s_setprio(0);
    __builtin_amdgcn_s_barrier();

    // ---------- phase 4: stage Bh1(t+2); vmcnt(6) once per K-tile
    if (t + 2 < NT) STG_B(t + 2, 1);
    if (t < NT - 2) {
      asm volatile("s_waitcnt vmcnt(6)" ::: "memory");
    } else if (t == NT - 2) {
      asm volatile("s_waitcnt vmcnt(0)" ::: "memory");
    }
    __builtin_amdgcn_sched_barrier(0);
    __builtin_amdgcn_s_barrier();
    __builtin_amdgcn_s_setprio(1);
#pragma unroll
    for (int mf = 0; mf < 4; ++mf)
#pragma unroll
      for (int nf = 0; nf < 2; ++nf) {
        acc[mf + 4][nf + 2] = __builtin_amdgcn_mfma_f32_16x16x32_bf16(a2[mf * 2], b2[nf * 2], acc[mf + 4][nf + 2], 0, 0, 0);
        acc[mf + 4][nf + 2] = __builtin_amdgcn_mfma_f32_16x16x32_bf16(a2[mf * 2 + 1], b2[nf * 2 + 1], acc[mf + 4][nf + 2], 0, 0, 0);
      }
    __builtin_amdgcn_s_setprio(0);
    __builtin_amdgcn_s_barrier();
  }
#undef STG_A
#undef STG_B

  // ---- epilogue: fused softmax (per 64-col head chunk = this wave's block)
  const int ocol0 = tn * 256 + wc * 64;
  const bool do_sm = SOFTMAX && (ocol0 < 1536);
#pragma unroll
  for (int mf = 0; mf < 8; ++mf) {
    if (do_sm) {
#pragma unroll
      for (int q = 0; q < 4; ++q) {
        float v0 = acc[mf][0][q], v1 = acc[mf][1][q];
        float v2 = acc[mf][2][q], v3 = acc[mf][3][q];
        float mx = fmaxf(fmaxf(v0, v1), fmaxf(v2, v3));
#pragma unroll
        for (int s = 1; s <= 8; s <<= 1) mx = fmaxf(mx, __shfl_xor(mx, s, 64));
        float e0 = __expf(v0 - mx), e1 = __expf(v1 - mx);
        float e2 = __expf(v2 - mx), e3 = __expf(v3 - mx);
        float sm = e0 + e1 + e2 + e3;
#pragma unroll
        for (int s = 1; s <= 8; s <<= 1) sm += __shfl_xor(sm, s, 64);
        float inv = 1.0f / sm;
        acc[mf][0][q] = e0 * inv; acc[mf][1][q] = e1 * inv;
        acc[mf][2][q] = e2 * inv; acc[mf][3][q] = e3 * inv;
      }
    }
    const int orow = tm * 256 + (mf >> 2) * 128 + wr * 64 + (mf & 3) * 16;
#pragma unroll
    for (int nf = 0; nf < 4; ++nf) {
      const int col = ocol0 + nf * 16 + lr;
      const float bv = BIAS ? bias[col] : 0.0f;
#pragma unroll
      for (int q = 0; q < 4; ++q) {
        const int row = orow + hi * 4 + q;
        const float v = acc[mf][nf][q] + bv;
        if (OUT_BF16) ((u16*)Cv)[(size_t)row * N + col] = f2b(v);
        else          ((float*)Cv)[(size_t)row * N + col] = v;
      }
    }
  }
}

// ---- context partials: partial[sp][bh][d][e] = sum_{n in split} k[n,d]*v[n,e] ----
#define NS 8
__global__ __launch_bounds__(256) void ctx_partial_kernel(const u16* __restrict__ qkv,
                                                          float* __restrict__ partial) {
  __shared__ u16 kT[64 * 136];
  __shared__ u16 vT[64 * 136];
  int bh = blockIdx.x / NS, sp = blockIdx.x % NS;
  int b = bh / 12, h = bh % 12;
  int tid = threadIdx.x, wave = tid >> 6, lane = tid & 63;
  int lr = lane & 15, lk = (lane >> 4) << 3;
  f32x4 acc[4] = {};
  int baseK = 768 + h * 64, baseV = 1536 + h * 64;

  for (int sub = 0; sub < 4; ++sub) {
    int nbase = b * 4096 + sp * 512 + sub * 128;
    __syncthreads();
#pragma unroll
    for (int it = 0; it < 4; ++it) {
      int s = it * 256 + tid;
      int n = s >> 3, c8 = (s & 7) * 8;
      u16x8 kv = *(const u16x8*)(qkv + (size_t)(nbase + n) * 2304 + baseK + c8);
      u16x8 vv = *(const u16x8*)(qkv + (size_t)(nbase + n) * 2304 + baseV + c8);
#pragma unroll
      for (int q = 0; q < 8; ++q) {
        kT[(c8 + q) * 136 + n] = kv[q];
        vT[(c8 + q) * 136 + n] = vv[q];
      }
    }
    __syncthreads();
#pragma unroll
    for (int ks = 0; ks < 4; ++ks) {
      bf16x8 af = *(const bf16x8*)&kT[(wave * 16 + lr) * 136 + ks * 32 + lk];
#pragma unroll
      for (int jt = 0; jt < 4; ++jt) {
        bf16x8 bfv = *(const bf16x8*)&vT[(jt * 16 + lr) * 136 + ks * 32 + lk];
        acc[jt] = __builtin_amdgcn_mfma_f32_16x16x32_bf16(af, bfv, acc[jt], 0, 0, 0);
      }
    }
  }
  float* dst = partial + ((size_t)sp * 96 + bh) * 4096;
#pragma unroll
  for (int jt = 0; jt < 4; ++jt)
#pragma unroll
    for (int q = 0; q < 4; ++q) {
      int d = wave * 16 + (lane >> 4) * 4 + q;
      int e = jt * 16 + lr;
      dst[d * 64 + e] = acc[jt][q];
    }
}

// ---- reduce partials -> ctxD[bh][d*64+e] bf16 (d-major) ----
__global__ __launch_bounds__(256) void ctx_reduce_kernel(const float* __restrict__ partial,
                                                         u16* __restrict__ ctxD) {
  int idx = blockIdx.x * 256 + threadIdx.x;   // 96*4096
  int bh = idx >> 12;
  int de = idx & 4095;
  float s = 0.0f;
#pragma unroll
  for (int sp = 0; sp < NS; ++sp) s += partial[((size_t)sp * 96 + bh) * 4096 + de];
  ctxD[(size_t)bh * 4096 + de] = f2b(s);
}

// ---- W2T[b][c'][h*64+d] = sum_e WprojT[c'][h*64+e] * ctxD[bh][d*64+e] ----
__global__ __launch_bounds__(256) void make_w2_kernel(const u16* __restrict__ WprojT,
                                                      const u16* __restrict__ ctxD,
                                                      u16* __restrict__ BT2) {
  __shared__ u16 qs[128 * 64];
  __shared__ u16 cs[64 * 64];
  int bid = blockIdx.x;
  int b = bid / 72, rest = bid % 72;
  int h = rest / 6, ct = rest % 6;
  int bh = b * 12 + h;
  int tid = threadIdx.x, wave = tid >> 6, lane = tid & 63;
  int lr = lane & 15, lk = (lane >> 4) << 3;
#pragma unroll
  for (int it = 0; it < 4; ++it) {
    int u = it * 256 + tid;
    int r = u >> 3, c8 = (u & 7) * 8;
    gload_lds16(WprojT + (size_t)(ct * 128 + r) * 768 + h * 64 + c8,
                &qs[(it * 256 + wave * 64) * 8]);
  }
#pragma unroll
  for (int it = 0; it < 2; ++it) {
    int u = it * 256 + tid;
    gload_lds16(ctxD + (size_t)bh * 4096 + u * 8, &cs[(it * 256 + wave * 64) * 8]);
  }
  asm volatile("s_waitcnt vmcnt(0)" ::: "memory");
  __syncthreads();
  f32x4 acc[2][4] = {};
#pragma unroll
  for (int ks = 0; ks < 2; ++ks) {
    bf16x8 bv[4];
#pragma unroll
    for (int jt = 0; jt < 4; ++jt) bv[jt] = *(const bf16x8*)&cs[(jt * 16 + lr) * 64 + ks * 32 + lk];
#pragma unroll
    for (int i = 0; i < 2; ++i) {
      bf16x8 af = *(const bf16x8*)&qs[(wave * 32 + i * 16 + lr) * 64 + ks * 32 + lk];
#pragma unroll
      for (int jt = 0; jt < 4; ++jt)
        acc[i][jt] = __builtin_amdgcn_mfma_f32_16x16x32_bf16(af, bv[jt], acc[i][jt], 0, 0, 0);
    }
  }
#pragma unroll
  for (int i = 0; i < 2; ++i)
#pragma unroll
    for (int jt = 0; jt < 4; ++jt)
#pragma unroll
      for (int q = 0; q < 4; ++q) {
        int cp = ct * 128 + wave * 32 + i * 16 + (lane >> 4) * 4 + q;
        int col = h * 64 + jt * 16 + lr;
        BT2[(size_t)b * 589824 + (size_t)cp * 768 + col] = f2b(acc[i][jt][q]);
      }
}

extern "C" void kernel_launch(void* const* d_in, const int* in_sizes, int n_in,
                              void* d_out, int out_size, void* d_ws, size_t ws_size,
                              hipStream_t stream) {
  const float* x = (const float*)d_in[0];
  const float* Wqkv = (const float*)d_in[1];
  const float* Wproj = (const float*)d_in[2];
  const float* bproj = (const float*)d_in[3];
  float* out = (float*)d_out;
  char* ws = (char*)d_ws;

  u16* xb      = (u16*)(ws);                     // 32768*768*2   = 50331648
  u16* WqkvT   = (u16*)(ws + 50331648);          // 2304*768*2    = 3538944
  u16* WprojT  = (u16*)(ws + 53870592);          // 768*768*2     = 1179648
  u16* qkv     = (u16*)(ws + 55050240);          // 32768*2304*2  = 150994944
  float* partial = (float*)(ws + 206045184);     // 8*96*4096*4   = 12582912
  u16* ctxD    = (u16*)(ws + 218628096);         // 96*4096*2     = 786432
  u16* BT2     = (u16*)(ws + 219414528);         // 8*768*768*2   = 9437184

  cast_x_kernel<<<2048, 256, 0, stream>>>(x, xb, (size_t)(32768ll * 768 / 8));
  transpose_cast_kernel<<<(768 / 32) * (2304 / 32), 256, 0, stream>>>(Wqkv, WqkvT, 768, 2304);
  transpose_cast_kernel<<<(768 / 32) * (768 / 32), 256, 0, stream>>>(Wproj, WprojT, 768, 768);

  // GEMM1: qkv = xb @ WqkvT^T, fused softmax on cols [0,1536)
  gemm256_kernel<true, false, true, false><<<(32768 / 256) * (2304 / 256), 512, 0, stream>>>(
      xb, WqkvT, (void*)qkv, nullptr, 2304, 768, 2304 / 256);

  ctx_partial_kernel<<<96 * NS, 256, 0, stream>>>(qkv, partial);
  ctx_reduce_kernel<<<(96 * 4096) / 256, 256, 0, stream>>>(partial, ctxD);
  make_w2_kernel<<<8 * 12 * 6, 256, 0, stream>>>(WprojT, ctxD, BT2);

  // GEMM3: out = q(from qkv, lda=2304) @ W2T_b^T + bias  (per-batch B)
  gemm256_kernel<false, true, false, true><<<(32768 / 256) * (768 / 256), 512, 0, stream>>>(
      qkv, BT2, (void*)out, bproj, 768, 2304, 768 / 256);
}

// Round 6
// 292.581 us; speedup vs baseline: 5.5406x; 1.0052x over previous
//
#include <hip/hip_runtime.h>

typedef unsigned short u16;
typedef unsigned int u32;
typedef __attribute__((ext_vector_type(4))) float f32x4;
typedef __attribute__((ext_vector_type(8))) short bf16x8;
typedef __attribute__((ext_vector_type(8))) u16 u16x8;

// ---- helpers ----
__device__ __forceinline__ u16 f2b(float f) {
  union { float f; u32 u; } v; v.f = f;
  u32 r = v.u + 0x7FFFu + ((v.u >> 16) & 1u);
  return (u16)(r >> 16);
}
__device__ __forceinline__ float b2f(u16 h) {
  union { u32 u; float f; } v; v.u = ((u32)h) << 16;
  return v.f;
}
__device__ __forceinline__ void gload_lds16(const void* g, void* lds) {
  __builtin_amdgcn_global_load_lds(
      (__attribute__((address_space(1))) void*)(void*)g,
      (__attribute__((address_space(3))) void*)lds, 16, 0, 0);
}

// ---- cast x (fp32 -> bf16), vectorized 8/thread ----
__global__ __launch_bounds__(256) void cast_x_kernel(const float* __restrict__ x,
                                                     u16* __restrict__ xb, size_t n8) {
  size_t i = (size_t)blockIdx.x * blockDim.x + threadIdx.x;
  size_t stride = (size_t)gridDim.x * blockDim.x;
  for (; i < n8; i += stride) {
    const float4* p = (const float4*)(x + i * 8);
    float4 a = p[0], b = p[1];
    u16x8 o;
    o[0] = f2b(a.x); o[1] = f2b(a.y); o[2] = f2b(a.z); o[3] = f2b(a.w);
    o[4] = f2b(b.x); o[5] = f2b(b.y); o[6] = f2b(b.z); o[7] = f2b(b.w);
    *(u16x8*)(xb + i * 8) = o;
  }
}

// ---- transpose + cast: W[R][C] (fp32) -> WT[C][R] (bf16) ----
__global__ __launch_bounds__(256) void transpose_cast_kernel(const float* __restrict__ W,
                                                             u16* __restrict__ WT,
                                                             int R, int C) {
  __shared__ u16 tile[32][33];
  int rt = R >> 5;
  int tr = blockIdx.x % rt, tc = blockIdx.x / rt;
  int r0 = tr * 32, c0 = tc * 32;
#pragma unroll
  for (int i = 0; i < 4; ++i) {
    int r = (threadIdx.x >> 5) + i * 8, c = threadIdx.x & 31;
    tile[r][c] = f2b(W[(size_t)(r0 + r) * C + c0 + c]);
  }
  __syncthreads();
#pragma unroll
  for (int i = 0; i < 4; ++i) {
    int c = (threadIdx.x >> 5) + i * 8, r = threadIdx.x & 31;
    WT[(size_t)(c0 + c) * R + r0 + r] = tile[r][c];
  }
}

// ============== 128x128 GEMM, 4 blocks/CU, never-drain pipeline ==============
// C[M][N] = A[M][K] * BT[N][K]^T ; bf16 in, fp32 acc ; K = 768 (NT=24, BK=32).
// 256 thr, 4 waves (2M x 2N); per-wave C = 64x64 = 4mf x 4nf (16x16 frags),
// acc = 64 regs; __launch_bounds__(256,4) caps total regs at 128 -> 4 waves/SIMD.
// LDS: A 2-ring + B 3-ring of 8KB tiles = 40 KB -> 4 blocks/CU.
// Per tile: 8 ds_read_b128 | stage A(t+1), B(t+2) | barrier | lgkmcnt(0) |
// 16 MFMA | vmcnt(2) (never drains; queue = B(t+1),A(t+1),B(t+2)) | barrier.
// Swizzle (64B rows): byte ^= ((byte>>7)&3)<<4, both sides (involution).
template <bool OUT_BF16, bool BIAS, bool SOFTMAX, bool BATCHB>
__global__ __launch_bounds__(256, 4) void gemm128_kernel(
    const u16* __restrict__ A, const u16* __restrict__ BT, void* __restrict__ Cv,
    const float* __restrict__ bias, int N, int lda, int ntile) {
  constexpr int K = 768;
  constexpr int NT = 24;
  __shared__ __align__(16) u16 As[2 * 4096];
  __shared__ __align__(16) u16 Bs[3 * 4096];
  const int tid = threadIdx.x;
  const int wave = tid >> 6, lane = tid & 63;
  const int lr = lane & 15, hi = lane >> 4;
  const int wr = wave >> 1, wc = wave & 1;

  // bijective XCD swizzle (grid % 8 == 0)
  const int cpx = gridDim.x >> 3;
  const int wg = (blockIdx.x & 7) * cpx + (blockIdx.x >> 3);
  const int tm = wg / ntile, tn = wg % ntile;

  const size_t rowA0 = (size_t)tm * 128;
  const size_t rowB0 = (size_t)tn * 128;
  const u16* BTb = BATCHB ? (BT + (size_t)(tm >> 5) * 589824) : BT;  // 4096 rows/batch

  // ---- staging: linear LDS dest (wave*512 u16), inverse-swizzled source
  const int dby = tid * 16;
  const int sby = dby ^ (((dby >> 7) & 3) << 4);
  const int srow = sby >> 6;           // 0..63
  const int scol = (sby & 63) >> 1;    // u16 col within 32-wide k slice
  const u16* pA = A + (rowA0 + srow) * (size_t)lda + scol;
  const u16* pB = BTb + (rowB0 + srow) * (size_t)K + scol;
  u16* Adst = As + wave * 512;
  u16* Bdst = Bs + wave * 512;

  // ---- read-side swizzled bases (flip depends only on lr bits 1..2)
  const int flip = ((lr >> 1) & 3) << 4;
  const int baseA = ((((wr * 64 + lr) * 64) + hi * 16) ^ flip) >> 1;  // u16 idx
  const int baseB = ((((wc * 64 + lr) * 64) + hi * 16) ^ flip) >> 1;

  f32x4 acc[4][4] = {};

#define STG_A(tt)                                                          \
  { const u16* _s = pA + (size_t)(tt) * 32;                                \
    u16* _d = Adst + ((tt) & 1) * 4096;                                    \
    gload_lds16(_s, _d); gload_lds16(_s + (size_t)64 * lda, _d + 2048); }
#define STG_B(tt)                                                          \
  { const u16* _s = pB + (size_t)(tt) * 32;                                \
    u16* _d = Bdst + ((tt) % 3) * 4096;                                    \
    gload_lds16(_s, _d); gload_lds16(_s + (size_t)64 * K, _d + 2048); }

  // prologue: A(0), B(0), B(1); wait A0+B0 (leave B1 in flight)
  STG_A(0); STG_B(0); STG_B(1);
  asm volatile("s_waitcnt vmcnt(2)" ::: "memory");
  __builtin_amdgcn_sched_barrier(0);
  __builtin_amdgcn_s_barrier();

#pragma unroll
  for (int t = 0; t < NT; ++t) {
    const u16* Ab = As + (t & 1) * 4096;
    const u16* Bb = Bs + (t % 3) * 4096;
    bf16x8 a0 = *(const bf16x8*)&Ab[baseA];
    bf16x8 a1 = *(const bf16x8*)&Ab[baseA + 512];
    bf16x8 a2 = *(const bf16x8*)&Ab[baseA + 1024];
    bf16x8 a3 = *(const bf16x8*)&Ab[baseA + 1536];
    bf16x8 b0 = *(const bf16x8*)&Bb[baseB];
    bf16x8 b1 = *(const bf16x8*)&Bb[baseB + 512];
    bf16x8 b2 = *(const bf16x8*)&Bb[baseB + 1024];
    bf16x8 b3 = *(const bf16x8*)&Bb[baseB + 1536];
    if (t + 1 < NT) STG_A(t + 1);
    if (t + 2 < NT) STG_B(t + 2);
    __builtin_amdgcn_s_barrier();
    asm volatile("s_waitcnt lgkmcnt(0)" ::: "memory");
    __builtin_amdgcn_sched_barrier(0);
    __builtin_amdgcn_s_setprio(1);
    acc[0][0] = __builtin_amdgcn_mfma_f32_16x16x32_bf16(a0, b0, acc[0][0], 0, 0, 0);
    acc[0][1] = __builtin_amdgcn_mfma_f32_16x16x32_bf16(a0, b1, acc[0][1], 0, 0, 0);
    acc[0][2] = __builtin_amdgcn_mfma_f32_16x16x32_bf16(a0, b2, acc[0][2], 0, 0, 0);
    acc[0][3] = __builtin_amdgcn_mfma_f32_16x16x32_bf16(a0, b3, acc[0][3], 0, 0, 0);
    acc[1][0] = __builtin_amdgcn_mfma_f32_16x16x32_bf16(a1, b0, acc[1][0], 0, 0, 0);
    acc[1][1] = __builtin_amdgcn_mfma_f32_16x16x32_bf16(a1, b1, acc[1][1], 0, 0, 0);
    acc[1][2] = __builtin_amdgcn_mfma_f32_16x16x32_bf16(a1, b2, acc[1][2], 0, 0, 0);
    acc[1][3] = __builtin_amdgcn_mfma_f32_16x16x32_bf16(a1, b3, acc[1][3], 0, 0, 0);
    acc[2][0] = __builtin_amdgcn_mfma_f32_16x16x32_bf16(a2, b0, acc[2][0], 0, 0, 0);
    acc[2][1] = __builtin_amdgcn_mfma_f32_16x16x32_bf16(a2, b1, acc[2][1], 0, 0, 0);
    acc[2][2] = __builtin_amdgcn_mfma_f32_16x16x32_bf16(a2, b2, acc[2][2], 0, 0, 0);
    acc[2][3] = __builtin_amdgcn_mfma_f32_16x16x32_bf16(a2, b3, acc[2][3], 0, 0, 0);
    acc[3][0] = __builtin_amdgcn_mfma_f32_16x16x32_bf16(a3, b0, acc[3][0], 0, 0, 0);
    acc[3][1] = __builtin_amdgcn_mfma_f32_16x16x32_bf16(a3, b1, acc[3][1], 0, 0, 0);
    acc[3][2] = __builtin_amdgcn_mfma_f32_16x16x32_bf16(a3, b2, acc[3][2], 0, 0, 0);
    acc[3][3] = __builtin_amdgcn_mfma_f32_16x16x32_bf16(a3, b3, acc[3][3], 0, 0, 0);
    __builtin_amdgcn_s_setprio(0);
    if (t < NT - 2) {
      asm volatile("s_waitcnt vmcnt(2)" ::: "memory");   // t+1 fully landed
    } else if (t == NT - 2) {
      asm volatile("s_waitcnt vmcnt(0)" ::: "memory");
    }
    __builtin_amdgcn_sched_barrier(0);
    if (t + 1 < NT) __builtin_amdgcn_s_barrier();
  }
#undef STG_A
#undef STG_B

  // ---- epilogue: fused softmax over this wave's 64-col head chunk + store
  const int ocol0 = tn * 128 + wc * 64;
  const int orow0 = tm * 128 + wr * 64;
  const bool do_sm = SOFTMAX && (ocol0 < 1536);
#pragma unroll
  for (int mf = 0; mf < 4; ++mf) {
    if (do_sm) {
#pragma unroll
      for (int q = 0; q < 4; ++q) {
        float v0 = acc[mf][0][q], v1 = acc[mf][1][q];
        float v2 = acc[mf][2][q], v3 = acc[mf][3][q];
        float mx = fmaxf(fmaxf(v0, v1), fmaxf(v2, v3));
#pragma unroll
        for (int s = 1; s <= 8; s <<= 1) mx = fmaxf(mx, __shfl_xor(mx, s, 64));
        float e0 = __expf(v0 - mx), e1 = __expf(v1 - mx);
        float e2 = __expf(v2 - mx), e3 = __expf(v3 - mx);
        float sm = e0 + e1 + e2 + e3;
#pragma unroll
        for (int s = 1; s <= 8; s <<= 1) sm += __shfl_xor(sm, s, 64);
        float inv = 1.0f / sm;
        acc[mf][0][q] = e0 * inv; acc[mf][1][q] = e1 * inv;
        acc[mf][2][q] = e2 * inv; acc[mf][3][q] = e3 * inv;
      }
    }
#pragma unroll
    for (int nf = 0; nf < 4; ++nf) {
      const int col = ocol0 + nf * 16 + lr;
      const float bv = BIAS ? bias[col] : 0.0f;
#pragma unroll
      for (int q = 0; q < 4; ++q) {
        const int row = orow0 + mf * 16 + hi * 4 + q;
        const float v = acc[mf][nf][q] + bv;
        if (OUT_BF16) ((u16*)Cv)[(size_t)row * N + col] = f2b(v);
        else          ((float*)Cv)[(size_t)row * N + col] = v;
      }
    }
  }
}

// ---- context partials: partial[sp][bh][d][e] = sum_{n in split} k[n,d]*v[n,e] ----
#define NS 8
__global__ __launch_bounds__(256) void ctx_partial_kernel(const u16* __restrict__ qkv,
                                                          float* __restrict__ partial) {
  __shared__ u16 kT[64 * 136];
  __shared__ u16 vT[64 * 136];
  int bh = blockIdx.x / NS, sp = blockIdx.x % NS;
  int b = bh / 12, h = bh % 12;
  int tid = threadIdx.x, wave = tid >> 6, lane = tid & 63;
  int lr = lane & 15, lk = (lane >> 4) << 3;
  f32x4 acc[4] = {};
  int baseK = 768 + h * 64, baseV = 1536 + h * 64;

  for (int sub = 0; sub < 4; ++sub) {
    int nbase = b * 4096 + sp * 512 + sub * 128;
    __syncthreads();
#pragma unroll
    for (int it = 0; it < 4; ++it) {
      int s = it * 256 + tid;
      int n = s >> 3, c8 = (s & 7) * 8;
      u16x8 kv = *(const u16x8*)(qkv + (size_t)(nbase + n) * 2304 + baseK + c8);
      u16x8 vv = *(const u16x8*)(qkv + (size_t)(nbase + n) * 2304 + baseV + c8);
#pragma unroll
      for (int q = 0; q < 8; ++q) {
        kT[(c8 + q) * 136 + n] = kv[q];
        vT[(c8 + q) * 136 + n] = vv[q];
      }
    }
    __syncthreads();
#pragma unroll
    for (int ks = 0; ks < 4; ++ks) {
      bf16x8 af = *(const bf16x8*)&kT[(wave * 16 + lr) * 136 + ks * 32 + lk];
#pragma unroll
      for (int jt = 0; jt < 4; ++jt) {
        bf16x8 bfv = *(const bf16x8*)&vT[(jt * 16 + lr) * 136 + ks * 32 + lk];
        acc[jt] = __builtin_amdgcn_mfma_f32_16x16x32_bf16(af, bfv, acc[jt], 0, 0, 0);
      }
    }
  }
  float* dst = partial + ((size_t)sp * 96 + bh) * 4096;
#pragma unroll
  for (int jt = 0; jt < 4; ++jt)
#pragma unroll
    for (int q = 0; q < 4; ++q) {
      int d = wave * 16 + (lane >> 4) * 4 + q;
      int e = jt * 16 + lr;
      dst[d * 64 + e] = acc[jt][q];
    }
}

// ---- reduce partials -> ctxD[bh][d*64+e] bf16 (d-major) ----
__global__ __launch_bounds__(256) void ctx_reduce_kernel(const float* __restrict__ partial,
                                                         u16* __restrict__ ctxD) {
  int idx = blockIdx.x * 256 + threadIdx.x;   // 96*4096
  int bh = idx >> 12;
  int de = idx & 4095;
  float s = 0.0f;
#pragma unroll
  for (int sp = 0; sp < NS; ++sp) s += partial[((size_t)sp * 96 + bh) * 4096 + de];
  ctxD[(size_t)bh * 4096 + de] = f2b(s);
}

// ---- W2T[b][c'][h*64+d] = sum_e WprojT[c'][h*64+e] * ctxD[bh][d*64+e] ----
__global__ __launch_bounds__(256) void make_w2_kernel(const u16* __restrict__ WprojT,
                                                      const u16* __restrict__ ctxD,
                                                      u16* __restrict__ BT2) {
  __shared__ u16 qs[128 * 64];
  __shared__ u16 cs[64 * 64];
  int bid = blockIdx.x;
  int b = bid / 72, rest = bid % 72;
  int h = rest / 6, ct = rest % 6;
  int bh = b * 12 + h;
  int tid = threadIdx.x, wave = tid >> 6, lane = tid & 63;
  int lr = lane & 15, lk = (lane >> 4) << 3;
#pragma unroll
  for (int it = 0; it < 4; ++it) {
    int u = it * 256 + tid;
    int r = u >> 3, c8 = (u & 7) * 8;
    gload_lds16(WprojT + (size_t)(ct * 128 + r) * 768 + h * 64 + c8,
                &qs[(it * 256 + wave * 64) * 8]);
  }
#pragma unroll
  for (int it = 0; it < 2; ++it) {
    int u = it * 256 + tid;
    gload_lds16(ctxD + (size_t)bh * 4096 + u * 8, &cs[(it * 256 + wave * 64) * 8]);
  }
  asm volatile("s_waitcnt vmcnt(0)" ::: "memory");
  __syncthreads();
  f32x4 acc[2][4] = {};
#pragma unroll
  for (int ks = 0; ks < 2; ++ks) {
    bf16x8 bv[4];
#pragma unroll
    for (int jt = 0; jt < 4; ++jt) bv[jt] = *(const bf16x8*)&cs[(jt * 16 + lr) * 64 + ks * 32 + lk];
#pragma unroll
    for (int i = 0; i < 2; ++i) {
      bf16x8 af = *(const bf16x8*)&qs[(wave * 32 + i * 16 + lr) * 64 + ks * 32 + lk];
#pragma unroll
      for (int jt = 0; jt < 4; ++jt)
        acc[i][jt] = __builtin_amdgcn_mfma_f32_16x16x32_bf16(af, bv[jt], acc[i][jt], 0, 0, 0);
    }
  }
#pragma unroll
  for (int i = 0; i < 2; ++i)
#pragma unroll
    for (int jt = 0; jt < 4; ++jt)
#pragma unroll
      for (int q = 0; q < 4; ++q) {
        int cp = ct * 128 + wave * 32 + i * 16 + (lane >> 4) * 4 + q;
        int col = h * 64 + jt * 16 + lr;
        BT2[(size_t)b * 589824 + (size_t)cp * 768 + col] = f2b(acc[i][jt][q]);
      }
}

extern "C" void kernel_launch(void* const* d_in, const int* in_sizes, int n_in,
                              void* d_out, int out_size, void* d_ws, size_t ws_size,
                              hipStream_t stream) {
  const float* x = (const float*)d_in[0];
  const float* Wqkv = (const float*)d_in[1];
  const float* Wproj = (const float*)d_in[2];
  const float* bproj = (const float*)d_in[3];
  float* out = (float*)d_out;
  char* ws = (char*)d_ws;

  u16* xb      = (u16*)(ws);                     // 32768*768*2   = 50331648
  u16* WqkvT   = (u16*)(ws + 50331648);          // 2304*768*2    = 3538944
  u16* WprojT  = (u16*)(ws + 53870592);          // 768*768*2     = 1179648
  u16* qkv     = (u16*)(ws + 55050240);          // 32768*2304*2  = 150994944
  float* partial = (float*)(ws + 206045184);     // 8*96*4096*4   = 12582912
  u16* ctxD    = (u16*)(ws + 218628096);         // 96*4096*2     = 786432
  u16* BT2     = (u16*)(ws + 219414528);         // 8*768*768*2   = 9437184

  cast_x_kernel<<<2048, 256, 0, stream>>>(x, xb, (size_t)(32768ll * 768 / 8));
  transpose_cast_kernel<<<(768 / 32) * (2304 / 32), 256, 0, stream>>>(Wqkv, WqkvT, 768, 2304);
  transpose_cast_kernel<<<(768 / 32) * (768 / 32), 256, 0, stream>>>(Wproj, WprojT, 768, 768);

  // GEMM1: qkv = xb @ WqkvT^T, fused softmax on cols [0,1536)
  gemm128_kernel<true, false, true, false><<<(32768 / 128) * (2304 / 128), 256, 0, stream>>>(
      xb, WqkvT, (void*)qkv, nullptr, 2304, 768, 2304 / 128);

  ctx_partial_kernel<<<96 * NS, 256, 0, stream>>>(qkv, partial);
  ctx_reduce_kernel<<<(96 * 4096) / 256, 256, 0, stream>>>(partial, ctxD);
  make_w2_kernel<<<8 * 12 * 6, 256, 0, stream>>>(WprojT, ctxD, BT2);

  // GEMM3: out = q(from qkv, lda=2304) @ W2T_b^T + bias  (per-batch B)
  gemm128_kernel<false, true, false, true><<<(32768 / 128) * (768 / 128), 256, 0, stream>>>(
      qkv, BT2, (void*)out, bproj, 768, 2304, 768 / 128);
}